// Round 1
// baseline (644.772 us; speedup 1.0000x reference)
//
#include <hip/hip_runtime.h>
#include <math.h>

#define BB 32      // batch
#define TDEC 64
#define UU 32      // utterances
#define TK 64
#define DD 512
#define VV 50257

// ---- workspace layout (float indices) ----
#define WS_LDEC   0           // B*D
#define WS_DEC_U  16384       // B*D
#define WS_DEC_T  32768       // B*D
#define WS_UOUT   49152       // B*D
#define WS_UATTN  65536       // B*U
#define WS_UIDX   66560       // B (int)
#define WS_TATTN  66592       // U*B*TK
#define WS_TOUT   132128      // B*D
#define WS_H      148512      // B*D
// total 164896 floats = ~660 KB

// ---- output layout (float indices) ----
#define OUT_VOCAB 0
#define OUT_TAD   1608224     // B*V
#define OUT_PGEN  1610272     // + B*TK
#define OUT_UCOV  1610304     // + B
#define OUT_NTC   1611328     // + B*U
#define OUT_UIDX  1676864     // + U*B*TK

__device__ __forceinline__ float wave_sum(float v) {
    #pragma unroll
    for (int off = 32; off > 0; off >>= 1) v += __shfl_xor(v, off, 64);
    return v;
}
__device__ __forceinline__ float wave_max(float v) {
    #pragma unroll
    for (int off = 32; off > 0; off >>= 1) v = fmaxf(v, __shfl_xor(v, off, 64));
    return v;
}
__device__ __forceinline__ float fast_tanh(float x) {
    float e2 = __expf(2.0f * x);
    return 1.0f - 2.0f * __builtin_amdgcn_rcpf(e2 + 1.0f);
}

// K1: layernorm of last timestep + both Wp projections
__global__ __launch_bounds__(256) void k1_ln_proj(
    const float* __restrict__ tf, const float* __restrict__ ln_g, const float* __restrict__ ln_b,
    const float* __restrict__ ua_Wp, const float* __restrict__ ua_bp,
    const float* __restrict__ ta_Wp, const float* __restrict__ ta_bp,
    float* __restrict__ ws)
{
    int b = blockIdx.x, tid = threadIdx.x, wid = tid >> 6, lane = tid & 63;
    __shared__ __align__(16) float ldec[DD];
    __shared__ float red[4];
    const float* x = tf + ((size_t)b * TDEC + (TDEC - 1)) * DD;
    float x0 = x[tid], x1 = x[tid + 256];

    float s = wave_sum(x0 + x1);
    if (lane == 0) red[wid] = s;
    __syncthreads();
    float mean = (red[0] + red[1] + red[2] + red[3]) * (1.0f / DD);
    __syncthreads();
    float d0 = x0 - mean, d1 = x1 - mean;
    s = wave_sum(d0 * d0 + d1 * d1);
    if (lane == 0) red[wid] = s;
    __syncthreads();
    float var = (red[0] + red[1] + red[2] + red[3]) * (1.0f / DD);
    float inv = rsqrtf(var + 1e-5f);
    float n0 = d0 * inv * ln_g[tid] + ln_b[tid];
    float n1 = d1 * inv * ln_g[tid + 256] + ln_b[tid + 256];
    ldec[tid] = n0; ldec[tid + 256] = n1;
    ws[WS_LDEC + b * DD + tid] = n0;
    ws[WS_LDEC + b * DD + tid + 256] = n1;
    __syncthreads();

    #pragma unroll
    for (int m = 0; m < 2; m++) {
        const float* Wp = m ? ta_Wp : ua_Wp;
        const float* bp = m ? ta_bp : ua_bp;
        float* dst = ws + (m ? WS_DEC_T : WS_DEC_U) + b * DD;
        for (int dd = tid; dd < DD; dd += 256) {
            const float4* wr = (const float4*)(Wp + (size_t)dd * DD);
            float acc = 0.f;
            for (int k = 0; k < DD / 4; k++) {
                float4 w = wr[k];
                acc += w.x * ldec[4*k] + w.y * ldec[4*k+1] + w.z * ldec[4*k+2] + w.w * ldec[4*k+3];
            }
            dst[dd] = acc + bp[dd];
        }
    }
}

// K2: utterance attention + u_cov + utter_index + p_gen
__global__ __launch_bounds__(256) void k2_uattn(
    const float* __restrict__ enc, const float* __restrict__ umask,
    const float* __restrict__ cov, const float* __restrict__ ua_v,
    const float* __restrict__ ua_wc, const float* __restrict__ pgen_W,
    const float* __restrict__ pgen_b,
    float* __restrict__ ws, float* __restrict__ out)
{
    int b = blockIdx.x, tid = threadIdx.x, wid = tid >> 6, lane = tid & 63;
    __shared__ __align__(16) float decu[DD], wcl[DD], vvl[DD], ldec[DD], uo[DD];
    __shared__ float sc[UU], attn[UU], red[4];
    decu[tid] = ws[WS_DEC_U + b * DD + tid]; decu[tid + 256] = ws[WS_DEC_U + b * DD + tid + 256];
    wcl[tid] = ua_wc[tid]; wcl[tid + 256] = ua_wc[tid + 256];
    vvl[tid] = ua_v[tid];  vvl[tid + 256] = ua_v[tid + 256];
    ldec[tid] = ws[WS_LDEC + b * DD + tid]; ldec[tid + 256] = ws[WS_LDEC + b * DD + tid + 256];
    __syncthreads();

    for (int u = wid; u < UU; u += 4) {
        float cb = cov[b * UU + u];
        const float* e = enc + ((size_t)b * UU + u) * DD;
        float p = 0.f;
        #pragma unroll
        for (int i = 0; i < DD / 64; i++) {
            int d = lane + i * 64;
            p += fast_tanh(e[d] + decu[d] + cb * wcl[d]) * vvl[d];
        }
        p = wave_sum(p);
        if (lane == 0) sc[u] = p;
    }
    __syncthreads();

    if (tid < 64) {
        float s = (tid < UU) ? sc[tid] : -INFINITY;
        float m = wave_max(s);
        float e = (tid < UU) ? __expf(s - m) : 0.f;
        float sum = wave_sum(e);
        float a_ = (e / sum) * ((tid < UU) ? umask[b * UU + tid] : 0.f);
        float nf = wave_sum(a_);
        float a = a_ / (nf == 0.f ? 1.f : nf);
        float av = (tid < UU) ? a : -INFINITY;
        float am = wave_max(av);
        unsigned long long ball = __ballot(av == am);
        int idx = __ffsll(ball) - 1;
        if (tid < UU) {
            attn[tid] = a;
            ws[WS_UATTN + b * UU + tid] = a;
            out[OUT_UCOV + b * UU + tid] = cov[b * UU + tid] + a;
        }
        if (tid == 0) {
            ((int*)ws)[WS_UIDX + b] = idx;
            out[OUT_UIDX + b] = (float)idx;
        }
    }
    __syncthreads();

    for (int d = tid; d < DD; d += 256) {
        float s = 0.f;
        #pragma unroll
        for (int u = 0; u < UU; u++) s += attn[u] * enc[((size_t)b * UU + u) * DD + d];
        uo[d] = s;
        ws[WS_UOUT + b * DD + d] = s;
    }
    __syncthreads();

    float pp = uo[tid] * pgen_W[tid] + uo[tid + 256] * pgen_W[tid + 256]
             + ldec[tid] * pgen_W[DD + tid] + ldec[tid + 256] * pgen_W[DD + tid + 256];
    pp = wave_sum(pp);
    if (lane == 0) red[wid] = pp;
    __syncthreads();
    if (tid == 0) {
        float t = red[0] + red[1] + red[2] + red[3] + pgen_b[0];
        out[OUT_PGEN + b] = 1.f / (1.f + __expf(-t));
    }
}

// K3: token attention scores + softmax + next_tok_cov (one block per (u,b))
__global__ __launch_bounds__(256) void k3_tattn(
    const float* __restrict__ tok, const float* __restrict__ tmask,
    const float* __restrict__ tcov, const float* __restrict__ ta_v,
    const float* __restrict__ ta_wc,
    float* __restrict__ ws, float* __restrict__ out)
{
    int blk = blockIdx.x;
    int u = blk >> 5, b = blk & 31;
    int tid = threadIdx.x, wid = tid >> 6, lane = tid & 63;
    __shared__ __align__(16) float dect[DD], wcl[DD], vvl[DD];
    __shared__ float sc[TK];
    dect[tid] = ws[WS_DEC_T + b * DD + tid]; dect[tid + 256] = ws[WS_DEC_T + b * DD + tid + 256];
    wcl[tid] = ta_wc[tid]; wcl[tid + 256] = ta_wc[tid + 256];
    vvl[tid] = ta_v[tid];  vvl[tid + 256] = ta_v[tid + 256];
    __syncthreads();

    const float* base = tok + ((size_t)(u * BB + b)) * TK * DD;
    const float* tcb = tcov + (size_t)(u * BB + b) * TK;

    for (int t = wid; t < TK; t += 4) {
        float tc = tcb[t];
        const float4* row = (const float4*)(base + (size_t)t * DD);
        float p = 0.f;
        #pragma unroll
        for (int i = 0; i < 2; i++) {
            int i4 = lane + i * 64;
            float4 x = row[i4];
            int d = i4 * 4;
            float4 dc = *(const float4*)(dect + d);
            float4 w  = *(const float4*)(wcl + d);
            float4 vv = *(const float4*)(vvl + d);
            p += fast_tanh(x.x + dc.x + tc * w.x) * vv.x;
            p += fast_tanh(x.y + dc.y + tc * w.y) * vv.y;
            p += fast_tanh(x.z + dc.z + tc * w.z) * vv.z;
            p += fast_tanh(x.w + dc.w + tc * w.w) * vv.w;
        }
        p = wave_sum(p);
        if (lane == 0) sc[t] = p;
    }
    __syncthreads();

    if (tid < 64) {
        float s = sc[tid];
        float m = wave_max(s);
        float e = __expf(s - m);
        float sum = wave_sum(e);
        float a_ = (e / sum) * tmask[(size_t)(u * BB + b) * TK + tid];
        float nf = wave_sum(a_);
        float a = a_ / (nf == 0.f ? 1.f : nf);
        ws[WS_TATTN + (size_t)(u * BB + b) * TK + tid] = a;
        out[OUT_NTC + (size_t)(u * BB + b) * TK + tid] = tcb[tid] + a;
    }
}

// K4: gather selected utterance, target_out, h = [target_out, ldec] @ out1_W^T + b
__global__ __launch_bounds__(256) void k4_select(
    const float* __restrict__ tok, const float* __restrict__ out1_W,
    const float* __restrict__ out1_b,
    float* __restrict__ ws, float* __restrict__ out)
{
    int b = blockIdx.x, tid = threadIdx.x;
    __shared__ __align__(16) float at[TK], to_[DD], ldec[DD];
    int u = ((const int*)ws)[WS_UIDX + b];
    if (tid < TK) {
        float a = ws[WS_TATTN + (size_t)(u * BB + b) * TK + tid];
        at[tid] = a;
        out[OUT_TAD + b * TK + tid] = a;
    }
    ldec[tid] = ws[WS_LDEC + b * DD + tid]; ldec[tid + 256] = ws[WS_LDEC + b * DD + tid + 256];
    __syncthreads();

    const float* base = tok + ((size_t)(u * BB + b)) * TK * DD;
    for (int d = tid; d < DD; d += 256) {
        float s = 0.f;
        #pragma unroll 8
        for (int t = 0; t < TK; t++) s += at[t] * base[(size_t)t * DD + d];
        to_[d] = s;
        ws[WS_TOUT + b * DD + d] = s;
    }
    __syncthreads();

    for (int dd = tid; dd < DD; dd += 256) {
        const float4* wr = (const float4*)(out1_W + (size_t)dd * 2 * DD);
        float acc = 0.f;
        for (int k = 0; k < DD / 4; k++) {
            float4 w = wr[k];
            acc += w.x * to_[4*k] + w.y * to_[4*k+1] + w.z * to_[4*k+2] + w.w * to_[4*k+3];
        }
        for (int k = 0; k < DD / 4; k++) {
            float4 w = wr[DD / 4 + k];
            acc += w.x * ldec[4*k] + w.y * ldec[4*k+1] + w.z * ldec[4*k+2] + w.w * ldec[4*k+3];
        }
        ws[WS_H + b * DD + dd] = acc + out1_b[dd];
    }
}

// K5: logits[b,v] = h[b,:] . W2[v,:] + b2[v] -> d_out vocab area
// thread = (kc in 0..7, b in 0..31); h slice in registers; split-K LDS reduce per 8-v tile
__global__ __launch_bounds__(256) void k5_gemv(
    const float* __restrict__ W2, const float* __restrict__ b2,
    const float* __restrict__ ws, float* __restrict__ out)
{
    int tid = threadIdx.x;
    int b = tid & 31, kc = tid >> 5;
    __shared__ float red[8 * 8 * 32];
    float h[64];
    {
        const float4* hp = (const float4*)(ws + WS_H + b * DD + kc * 64);
        #pragma unroll
        for (int i = 0; i < 16; i++) {
            float4 v = hp[i];
            h[4*i] = v.x; h[4*i+1] = v.y; h[4*i+2] = v.z; h[4*i+3] = v.w;
        }
    }
    const int numTiles = (VV + 7) / 8;
    for (int tile = blockIdx.x; tile < numTiles; tile += gridDim.x) {
        int v0 = tile * 8;
        float acc[8];
        #pragma unroll
        for (int j = 0; j < 8; j++) acc[j] = 0.f;
        #pragma unroll
        for (int j = 0; j < 8; j++) {
            int v = v0 + j;
            if (v < VV) {
                const float4* wr = (const float4*)(W2 + (size_t)v * DD + kc * 64);
                float a = 0.f;
                #pragma unroll
                for (int i = 0; i < 16; i++) {
                    float4 w = wr[i];
                    a += w.x * h[4*i] + w.y * h[4*i+1] + w.z * h[4*i+2] + w.w * h[4*i+3];
                }
                acc[j] = a;
            }
        }
        #pragma unroll
        for (int j = 0; j < 8; j++) red[(j * 8 + kc) * 32 + b] = acc[j];
        __syncthreads();
        {
            int bb = tid >> 3, j = tid & 7;
            int v = v0 + j;
            if (v < VV) {
                float s = 0.f;
                #pragma unroll
                for (int k = 0; k < 8; k++) s += red[(j * 8 + k) * 32 + bb];
                out[(size_t)bb * VV + v] = s + b2[v];
            }
        }
        __syncthreads();
    }
}

// K6: in-place row softmax over V
__global__ __launch_bounds__(1024) void k6_softmax(float* __restrict__ out)
{
    int r = blockIdx.x, tid = threadIdx.x;
    float* p = out + (size_t)r * VV;
    __shared__ float red[16];
    float m = -INFINITY;
    for (int i = tid; i < VV; i += 1024) m = fmaxf(m, p[i]);
    m = wave_max(m);
    if ((tid & 63) == 0) red[tid >> 6] = m;
    __syncthreads();
    if (tid < 64) {
        float t = (tid < 16) ? red[tid] : -INFINITY;
        t = wave_max(t);
        if (tid == 0) red[0] = t;
    }
    __syncthreads();
    m = red[0];
    __syncthreads();
    float s = 0.f;
    for (int i = tid; i < VV; i += 1024) {
        float e = __expf(p[i] - m);
        p[i] = e;
        s += e;
    }
    s = wave_sum(s);
    if ((tid & 63) == 0) red[tid >> 6] = s;
    __syncthreads();
    if (tid < 64) {
        float t = (tid < 16) ? red[tid] : 0.f;
        t = wave_sum(t);
        if (tid == 0) red[0] = t;
    }
    __syncthreads();
    float inv = 1.f / red[0];
    for (int i = tid; i < VV; i += 1024) p[i] *= inv;
}

extern "C" void kernel_launch(void* const* d_in, const int* in_sizes, int n_in,
                              void* d_out, int out_size, void* d_ws, size_t ws_size,
                              hipStream_t stream) {
    const float* tf      = (const float*)d_in[0];
    const float* enc     = (const float*)d_in[2];
    const float* umask   = (const float*)d_in[3];
    const float* tok     = (const float*)d_in[4];
    const float* tmask   = (const float*)d_in[5];
    const float* cov     = (const float*)d_in[6];
    const float* tcov    = (const float*)d_in[7];
    const float* ua_Wp   = (const float*)d_in[8];
    const float* ua_bp   = (const float*)d_in[9];
    const float* ua_v    = (const float*)d_in[10];
    const float* ua_wc   = (const float*)d_in[11];
    const float* ta_Wp   = (const float*)d_in[12];
    const float* ta_bp   = (const float*)d_in[13];
    const float* ta_v    = (const float*)d_in[14];
    const float* ta_wc   = (const float*)d_in[15];
    const float* pgen_W  = (const float*)d_in[16];
    const float* pgen_b  = (const float*)d_in[17];
    const float* out1_W  = (const float*)d_in[18];
    const float* out1_b  = (const float*)d_in[19];
    const float* out2_W  = (const float*)d_in[20];
    const float* out2_b  = (const float*)d_in[21];
    const float* ln_g    = (const float*)d_in[22];
    const float* ln_b    = (const float*)d_in[23];

    float* ws  = (float*)d_ws;
    float* out = (float*)d_out;

    k1_ln_proj<<<dim3(BB), dim3(256), 0, stream>>>(tf, ln_g, ln_b, ua_Wp, ua_bp, ta_Wp, ta_bp, ws);
    k2_uattn<<<dim3(BB), dim3(256), 0, stream>>>(enc, umask, cov, ua_v, ua_wc, pgen_W, pgen_b, ws, out);
    k3_tattn<<<dim3(UU * BB), dim3(256), 0, stream>>>(tok, tmask, tcov, ta_v, ta_wc, ws, out);
    k4_select<<<dim3(BB), dim3(256), 0, stream>>>(tok, out1_W, out1_b, ws, out);
    k5_gemv<<<dim3(1024), dim3(256), 0, stream>>>(out2_W, out2_b, ws, out);
    k6_softmax<<<dim3(BB), dim3(1024), 0, stream>>>(out);
}

// Round 2
// 475.360 us; speedup vs baseline: 1.3564x; 1.3564x over previous
//
#include <hip/hip_runtime.h>
#include <math.h>

#define BB 32
#define TDEC 64
#define UU 32
#define TK 64
#define DD 512
#define VV 50257
#define NT5 3142      // ceil(VV/16)
#define K5_GRID 1024

// ---- workspace layout (float indices) ----
#define WS_LDEC   0          // B*D
#define WS_DEC_U  16384      // B*D
#define WS_DEC_T  32768      // B*D
#define WS_UATTN  49152      // B*U
#define WS_UIDX   50176      // B (int)
#define WS_TSC    50208      // U*B*TK raw scores
#define WS_TATTN  115744     // U*B*TK
#define WS_TOUT   181280     // B*D
#define WS_H      197664     // B*D
#define WS_PSUM   214048     // K5_GRID*32
#define WS_SUMS   246816     // 32 (stores 1/sum)

// ---- output layout (float indices) ----
#define OUT_VOCAB 0
#define OUT_TAD   1608224
#define OUT_PGEN  1610272
#define OUT_UCOV  1610304
#define OUT_NTC   1611328
#define OUT_UIDX  1676864

__device__ __forceinline__ float wave_sum(float v) {
    #pragma unroll
    for (int off = 32; off > 0; off >>= 1) v += __shfl_xor(v, off, 64);
    return v;
}
__device__ __forceinline__ float wave_max(float v) {
    #pragma unroll
    for (int off = 32; off > 0; off >>= 1) v = fmaxf(v, __shfl_xor(v, off, 64));
    return v;
}
__device__ __forceinline__ float fast_tanh(float x) {
    float e2 = __expf(2.0f * x);
    return 1.0f - 2.0f * __builtin_amdgcn_rcpf(e2 + 1.0f);
}

// K1: LN of last timestep (recomputed per block) + slice of both Wp projections.
// grid 256: b = blk>>3, slice = blk&7; slice covers 128 rows of [ua_Wp; ta_Wp].
__global__ __launch_bounds__(256) void k1_ln_proj(
    const float* __restrict__ tf, const float* __restrict__ ln_g, const float* __restrict__ ln_b,
    const float* __restrict__ ua_Wp, const float* __restrict__ ua_bp,
    const float* __restrict__ ta_Wp, const float* __restrict__ ta_bp,
    float* __restrict__ ws)
{
    int b = blockIdx.x >> 3, slice = blockIdx.x & 7;
    int tid = threadIdx.x, wid = tid >> 6, lane = tid & 63;
    __shared__ __align__(16) float ldec[DD];
    __shared__ float red[4];
    const float* x = tf + ((size_t)b * TDEC + (TDEC - 1)) * DD;
    float x0 = x[tid], x1 = x[tid + 256];

    float s = wave_sum(x0 + x1);
    if (lane == 0) red[wid] = s;
    __syncthreads();
    float mean = (red[0] + red[1] + red[2] + red[3]) * (1.0f / DD);
    __syncthreads();
    float d0 = x0 - mean, d1 = x1 - mean;
    s = wave_sum(d0 * d0 + d1 * d1);
    if (lane == 0) red[wid] = s;
    __syncthreads();
    float var = (red[0] + red[1] + red[2] + red[3]) * (1.0f / DD);
    float inv = rsqrtf(var + 1e-5f);
    float n0 = d0 * inv * ln_g[tid] + ln_b[tid];
    float n1 = d1 * inv * ln_g[tid + 256] + ln_b[tid + 256];
    ldec[tid] = n0; ldec[tid + 256] = n1;
    if (slice == 0) {
        ws[WS_LDEC + b * DD + tid] = n0;
        ws[WS_LDEC + b * DD + tid + 256] = n1;
    }
    __syncthreads();

    int r = slice * 128 + (tid >> 1);   // 0..1023
    int m = r >> 9, rr = r & 511;
    int kh = tid & 1;
    const float* Wp = m ? ta_Wp : ua_Wp;
    const float* bp = m ? ta_bp : ua_bp;
    const float4* wr = (const float4*)(Wp + (size_t)rr * DD + kh * 256);
    const float4* hl = (const float4*)ldec + kh * 64;
    float acc = 0.f;
    #pragma unroll 8
    for (int i = 0; i < 64; i++) {
        float4 w = wr[i]; float4 h = hl[i];
        acc += w.x * h.x + w.y * h.y + w.z * h.z + w.w * h.w;
    }
    float tot = acc + __shfl_xor(acc, 1, 64);
    if (kh == 0) {
        float* dst = ws + (m ? WS_DEC_T : WS_DEC_U) + b * DD + rr;
        *dst = tot + bp[rr];
    }
}

// K2: utterance attention + u_cov + utter_index + p_gen
__global__ __launch_bounds__(256) void k2_uattn(
    const float* __restrict__ enc, const float* __restrict__ umask,
    const float* __restrict__ cov, const float* __restrict__ ua_v,
    const float* __restrict__ ua_wc, const float* __restrict__ pgen_W,
    const float* __restrict__ pgen_b,
    float* __restrict__ ws, float* __restrict__ out)
{
    int b = blockIdx.x, tid = threadIdx.x, wid = tid >> 6, lane = tid & 63;
    __shared__ __align__(16) float decu[DD], wcl[DD], vvl[DD], ldec[DD], uo[DD];
    __shared__ float sc[UU], attn[UU], red[4];
    decu[tid] = ws[WS_DEC_U + b * DD + tid]; decu[tid + 256] = ws[WS_DEC_U + b * DD + tid + 256];
    wcl[tid] = ua_wc[tid]; wcl[tid + 256] = ua_wc[tid + 256];
    vvl[tid] = ua_v[tid];  vvl[tid + 256] = ua_v[tid + 256];
    ldec[tid] = ws[WS_LDEC + b * DD + tid]; ldec[tid + 256] = ws[WS_LDEC + b * DD + tid + 256];
    __syncthreads();

    for (int u = wid; u < UU; u += 4) {
        float cb = cov[b * UU + u];
        const float* e = enc + ((size_t)b * UU + u) * DD;
        float p = 0.f;
        #pragma unroll
        for (int i = 0; i < DD / 64; i++) {
            int d = lane + i * 64;
            p += fast_tanh(e[d] + decu[d] + cb * wcl[d]) * vvl[d];
        }
        p = wave_sum(p);
        if (lane == 0) sc[u] = p;
    }
    __syncthreads();

    if (tid < 64) {
        float s = (tid < UU) ? sc[tid] : -INFINITY;
        float m = wave_max(s);
        float e = (tid < UU) ? __expf(s - m) : 0.f;
        float sum = wave_sum(e);
        float a_ = (e / sum) * ((tid < UU) ? umask[b * UU + tid] : 0.f);
        float nf = wave_sum(a_);
        float a = a_ / (nf == 0.f ? 1.f : nf);
        float av = (tid < UU) ? a : -INFINITY;
        float am = wave_max(av);
        unsigned long long ball = __ballot(av == am);
        int idx = __ffsll(ball) - 1;
        if (tid < UU) {
            attn[tid] = a;
            ws[WS_UATTN + b * UU + tid] = a;
            out[OUT_UCOV + b * UU + tid] = cov[b * UU + tid] + a;
        }
        if (tid == 0) {
            ((int*)ws)[WS_UIDX + b] = idx;
            out[OUT_UIDX + b] = (float)idx;
        }
    }
    __syncthreads();

    for (int d = tid; d < DD; d += 256) {
        float s = 0.f;
        #pragma unroll
        for (int u = 0; u < UU; u++) s += attn[u] * enc[((size_t)b * UU + u) * DD + d];
        uo[d] = s;
    }
    __syncthreads();

    float pp = uo[tid] * pgen_W[tid] + uo[tid + 256] * pgen_W[tid + 256]
             + ldec[tid] * pgen_W[DD + tid] + ldec[tid + 256] * pgen_W[DD + tid + 256];
    pp = wave_sum(pp);
    if (lane == 0) red[wid] = pp;
    __syncthreads();
    if (tid == 0) {
        float t = red[0] + red[1] + red[2] + red[3] + pgen_b[0];
        out[OUT_PGEN + b] = 1.f / (1.f + __expf(-t));
    }
}

// K3a: token attention raw scores. grid 2048: u = blk>>6, b = (blk&63)>>1, hf = blk&1.
// Each wave: 8 rows, all 16 float4 loads issued up front; dec/wc/v per-lane in regs.
__global__ __launch_bounds__(256, 4) void k3a_tscore(
    const float* __restrict__ tok, const float* __restrict__ tcov,
    const float* __restrict__ ta_v, const float* __restrict__ ta_wc,
    float* __restrict__ ws)
{
    int blk = blockIdx.x;
    int u = blk >> 6, r = blk & 63, b = r >> 1, hf = r & 1;
    int tid = threadIdx.x, wid = tid >> 6, lane = tid & 63;

    const float4* dec4 = (const float4*)(ws + WS_DEC_T + b * DD);
    const float4* wc4  = (const float4*)ta_wc;
    const float4* vv4  = (const float4*)ta_v;
    float4 dc0 = dec4[lane], dc1 = dec4[lane + 64];
    float4 wc0 = wc4[lane],  wc1 = wc4[lane + 64];
    float4 vv0 = vv4[lane],  vv1 = vv4[lane + 64];

    const float* base = tok + ((size_t)(u * BB + b)) * TK * DD;
    const float* tcb  = tcov + (size_t)(u * BB + b) * TK;
    int t0 = hf * 32 + wid * 8;

    float4 x[8][2];
    float tc[8];
    #pragma unroll
    for (int j = 0; j < 8; j++) {
        const float4* row = (const float4*)(base + (size_t)(t0 + j) * DD);
        x[j][0] = row[lane];
        x[j][1] = row[lane + 64];
        tc[j] = tcb[t0 + j];
    }
    #pragma unroll
    for (int j = 0; j < 8; j++) {
        float p = 0.f;
        float4 a = x[j][0], c = x[j][1];
        float t_ = tc[j];
        p += fast_tanh(a.x + dc0.x + t_ * wc0.x) * vv0.x;
        p += fast_tanh(a.y + dc0.y + t_ * wc0.y) * vv0.y;
        p += fast_tanh(a.z + dc0.z + t_ * wc0.z) * vv0.z;
        p += fast_tanh(a.w + dc0.w + t_ * wc0.w) * vv0.w;
        p += fast_tanh(c.x + dc1.x + t_ * wc1.x) * vv1.x;
        p += fast_tanh(c.y + dc1.y + t_ * wc1.y) * vv1.y;
        p += fast_tanh(c.z + dc1.z + t_ * wc1.z) * vv1.z;
        p += fast_tanh(c.w + dc1.w + t_ * wc1.w) * vv1.w;
        p = wave_sum(p);
        if (lane == 0) ws[WS_TSC + (size_t)(u * BB + b) * TK + t0 + j] = p;
    }
}

// K3b: per-(u,b) softmax over 64 scores + next_tok_cov. 256 blocks x 4 waves = 1024 rows.
__global__ __launch_bounds__(256) void k3b_tsoftmax(
    const float* __restrict__ tmask, const float* __restrict__ tcov,
    float* __restrict__ ws, float* __restrict__ out)
{
    int tid = threadIdx.x, wid = tid >> 6, lane = tid & 63;
    int g = blockIdx.x * 4 + wid;  // 0..1023 = u*32+b
    float s = ws[WS_TSC + (size_t)g * TK + lane];
    float m = wave_max(s);
    float e = __expf(s - m);
    float sum = wave_sum(e);
    float a_ = (e / sum) * tmask[(size_t)g * TK + lane];
    float nf = wave_sum(a_);
    float a = a_ / (nf == 0.f ? 1.f : nf);
    ws[WS_TATTN + (size_t)g * TK + lane] = a;
    out[OUT_NTC + (size_t)g * TK + lane] = tcov[(size_t)g * TK + lane] + a;
}

// K4a: gather selected utterance attn, write TAD, compute target_out -> ws
__global__ __launch_bounds__(256) void k4a_gather(
    const float* __restrict__ tok, float* __restrict__ ws, float* __restrict__ out)
{
    int b = blockIdx.x, tid = threadIdx.x;
    __shared__ float at[TK];
    int u = ((const int*)ws)[WS_UIDX + b];
    if (tid < TK) {
        float a = ws[WS_TATTN + (size_t)(u * BB + b) * TK + tid];
        at[tid] = a;
        out[OUT_TAD + b * TK + tid] = a;
    }
    __syncthreads();
    const float* base = tok + ((size_t)(u * BB + b)) * TK * DD;
    float a0 = 0.f, a1 = 0.f;
    #pragma unroll 8
    for (int t = 0; t < TK; t++) {
        float a = at[t];
        a0 += a * base[(size_t)t * DD + tid];
        a1 += a * base[(size_t)t * DD + tid + 256];
    }
    ws[WS_TOUT + b * DD + tid] = a0;
    ws[WS_TOUT + b * DD + tid + 256] = a1;
}

// K4b: h = [target_out, ldec] @ out1_W^T + b. grid 128: slice = blk>>5, b = blk&31.
__global__ __launch_bounds__(256) void k4b_h(
    const float* __restrict__ out1_W, const float* __restrict__ out1_b,
    float* __restrict__ ws)
{
    int slice = blockIdx.x >> 5, b = blockIdx.x & 31;
    int tid = threadIdx.x;
    __shared__ __align__(16) float hcat[2 * DD];
    hcat[tid]       = ws[WS_TOUT + b * DD + tid];
    hcat[tid + 256] = ws[WS_TOUT + b * DD + tid + 256];
    hcat[tid + 512] = ws[WS_LDEC + b * DD + tid];
    hcat[tid + 768] = ws[WS_LDEC + b * DD + tid + 256];
    __syncthreads();

    int row = slice * 128 + (tid >> 1);
    int kh = tid & 1;
    const float4* wr = (const float4*)(out1_W + (size_t)row * (2 * DD) + kh * 512);
    const float4* hl = (const float4*)hcat + kh * 128;
    float acc = 0.f;
    #pragma unroll 8
    for (int i = 0; i < 128; i++) {
        float4 w = wr[i]; float4 h = hl[i];
        acc += w.x * h.x + w.y * h.y + w.z * h.z + w.w * h.w;
    }
    float tot = acc + __shfl_xor(acc, 1, 64);
    if (kh == 0) ws[WS_H + b * DD + row] = tot + out1_b[row];
}

// K5: exp(logits) -> out vocab area + per-block partial exp-sums.
// 512 threads: b = tid&31, kc = tid>>4? no: kc = tid>>5 (16 k-chunks of 32).
// h chunk (8 float4) held in registers; 16-v tiles; LDS split-k reduce (pad 33).
__global__ __launch_bounds__(512, 4) void k5_gemv(
    const float* __restrict__ W2, const float* __restrict__ b2,
    float* __restrict__ ws, float* __restrict__ out)
{
    int tid = threadIdx.x;
    int b = tid & 31, kc = tid >> 5;          // kc 0..15
    __shared__ float red[16 * 16 * 33];       // [kc][j][b pad33]
    float4 hr[8];
    {
        const float4* hp = (const float4*)(ws + WS_H + b * DD + kc * 32);
        #pragma unroll
        for (int i = 0; i < 8; i++) hr[i] = hp[i];
    }
    int jj = tid & 15, bb = tid >> 4;         // reduce-phase mapping
    float es = 0.f;

    for (int tile = blockIdx.x; tile < NT5; tile += K5_GRID) {
        int v0 = tile * 16;
        float acc[16];
        #pragma unroll
        for (int j = 0; j < 16; j++) acc[j] = 0.f;
        #pragma unroll 2
        for (int j = 0; j < 16; j++) {
            int v = v0 + j;
            if (v < VV) {
                const float4* wr = (const float4*)(W2 + (size_t)v * DD + kc * 32);
                float a = 0.f;
                #pragma unroll
                for (int i = 0; i < 8; i++) {
                    float4 w = wr[i];
                    a += w.x * hr[i].x + w.y * hr[i].y + w.z * hr[i].z + w.w * hr[i].w;
                }
                acc[j] = a;
            }
        }
        #pragma unroll
        for (int j = 0; j < 16; j++) red[(kc * 16 + j) * 33 + b] = acc[j];
        __syncthreads();
        {
            int v = v0 + jj;
            if (v < VV) {
                float s = 0.f;
                #pragma unroll
                for (int k = 0; k < 16; k++) s += red[(k * 16 + jj) * 33 + bb];
                float e = __expf(s + b2[v]);
                out[(size_t)bb * VV + v] = e;
                es += e;
            }
        }
        __syncthreads();
    }
    // reduce es over jj within each 16-lane group, write per-block partials
    #pragma unroll
    for (int off = 1; off < 16; off <<= 1) es += __shfl_xor(es, off, 64);
    if (jj == 0) ws[WS_PSUM + blockIdx.x * 32 + bb] = es;
}

// K_sum: reduce psum[K5_GRID][32] -> ws_sums[32] (stores reciprocal)
__global__ __launch_bounds__(256) void k_sum(float* __restrict__ ws)
{
    int tid = threadIdx.x;
    int b = tid & 31, c = tid >> 5;  // 8 chunks of 128 blocks
    __shared__ float red8[8][32];
    float p = 0.f;
    for (int g = c * 128; g < (c + 1) * 128; g++) p += ws[WS_PSUM + g * 32 + b];
    red8[c][b] = p;
    __syncthreads();
    if (tid < 32) {
        float s = 0.f;
        #pragma unroll
        for (int c2 = 0; c2 < 8; c2++) s += red8[c2][tid];
        ws[WS_SUMS + tid] = 1.0f / s;
    }
}

// K_scale: vocab_dist = exp(logit) * (1/sum_b)
__global__ __launch_bounds__(256) void k_scale(const float* __restrict__ ws, float* __restrict__ out)
{
    int b = blockIdx.y;
    int v = blockIdx.x * 256 + threadIdx.x;
    if (v < VV) out[(size_t)b * VV + v] *= ws[WS_SUMS + b];
}

extern "C" void kernel_launch(void* const* d_in, const int* in_sizes, int n_in,
                              void* d_out, int out_size, void* d_ws, size_t ws_size,
                              hipStream_t stream) {
    const float* tf      = (const float*)d_in[0];
    const float* enc     = (const float*)d_in[2];
    const float* umask   = (const float*)d_in[3];
    const float* tok     = (const float*)d_in[4];
    const float* tmask   = (const float*)d_in[5];
    const float* cov     = (const float*)d_in[6];
    const float* tcov    = (const float*)d_in[7];
    const float* ua_Wp   = (const float*)d_in[8];
    const float* ua_bp   = (const float*)d_in[9];
    const float* ua_v    = (const float*)d_in[10];
    const float* ua_wc   = (const float*)d_in[11];
    const float* ta_Wp   = (const float*)d_in[12];
    const float* ta_bp   = (const float*)d_in[13];
    const float* ta_v    = (const float*)d_in[14];
    const float* ta_wc   = (const float*)d_in[15];
    const float* pgen_W  = (const float*)d_in[16];
    const float* pgen_b  = (const float*)d_in[17];
    const float* out1_W  = (const float*)d_in[18];
    const float* out1_b  = (const float*)d_in[19];
    const float* out2_W  = (const float*)d_in[20];
    const float* out2_b  = (const float*)d_in[21];
    const float* ln_g    = (const float*)d_in[22];
    const float* ln_b    = (const float*)d_in[23];

    float* ws  = (float*)d_ws;
    float* out = (float*)d_out;

    k1_ln_proj<<<dim3(256), dim3(256), 0, stream>>>(tf, ln_g, ln_b, ua_Wp, ua_bp, ta_Wp, ta_bp, ws);
    k2_uattn<<<dim3(BB), dim3(256), 0, stream>>>(enc, umask, cov, ua_v, ua_wc, pgen_W, pgen_b, ws, out);
    k3a_tscore<<<dim3(2048), dim3(256), 0, stream>>>(tok, tcov, ta_v, ta_wc, ws);
    k3b_tsoftmax<<<dim3(256), dim3(256), 0, stream>>>(tmask, tcov, ws, out);
    k4a_gather<<<dim3(BB), dim3(256), 0, stream>>>(tok, ws, out);
    k4b_h<<<dim3(128), dim3(256), 0, stream>>>(out1_W, out1_b, ws);
    k5_gemv<<<dim3(K5_GRID), dim3(512), 0, stream>>>(out2_W, out2_b, ws, out);
    k_sum<<<dim3(1), dim3(256), 0, stream>>>(ws);
    k_scale<<<dim3(197, 32), dim3(256), 0, stream>>>(ws, out);
}

// Round 3
// 458.189 us; speedup vs baseline: 1.4072x; 1.0375x over previous
//
#include <hip/hip_runtime.h>
#include <math.h>

#define BB 32
#define TDEC 64
#define UU 32
#define TK 64
#define DD 512
#define VV 50257
#define N5TILE 256
#define K5_GRID 197   // ceil(VV/256)

// ---- workspace layout (float indices) ----
#define WS_LDEC   0          // B*D
#define WS_DEC_U  16384      // B*D
#define WS_DEC_T  32768      // B*D
#define WS_UATTN  49152      // B*U
#define WS_UIDX   50176      // B (int)
#define WS_TSC    50208      // U*B*TK raw scores
#define WS_TATTN  115744     // U*B*TK
#define WS_TOUT   181280     // B*D
#define WS_H      197664     // B*D
#define WS_PSUM   214048     // K5_GRID*32
#define WS_SUMS   246816     // 32 (stores 1/sum)

// ---- output layout (float indices) ----
#define OUT_VOCAB 0
#define OUT_TAD   1608224
#define OUT_PGEN  1610272
#define OUT_UCOV  1610304
#define OUT_NTC   1611328
#define OUT_UIDX  1676864

__device__ __forceinline__ float wave_sum(float v) {
    #pragma unroll
    for (int off = 32; off > 0; off >>= 1) v += __shfl_xor(v, off, 64);
    return v;
}
__device__ __forceinline__ float wave_max(float v) {
    #pragma unroll
    for (int off = 32; off > 0; off >>= 1) v = fmaxf(v, __shfl_xor(v, off, 64));
    return v;
}
__device__ __forceinline__ float fast_tanh(float x) {
    float e2 = __expf(2.0f * x);
    return 1.0f - 2.0f * __builtin_amdgcn_rcpf(e2 + 1.0f);
}

// K1: LN of last timestep (recomputed per block) + slice of both Wp projections.
__global__ __launch_bounds__(256) void k1_ln_proj(
    const float* __restrict__ tf, const float* __restrict__ ln_g, const float* __restrict__ ln_b,
    const float* __restrict__ ua_Wp, const float* __restrict__ ua_bp,
    const float* __restrict__ ta_Wp, const float* __restrict__ ta_bp,
    float* __restrict__ ws)
{
    int b = blockIdx.x >> 3, slice = blockIdx.x & 7;
    int tid = threadIdx.x, wid = tid >> 6, lane = tid & 63;
    __shared__ __align__(16) float ldec[DD];
    __shared__ float red[4];
    const float* x = tf + ((size_t)b * TDEC + (TDEC - 1)) * DD;
    float x0 = x[tid], x1 = x[tid + 256];

    float s = wave_sum(x0 + x1);
    if (lane == 0) red[wid] = s;
    __syncthreads();
    float mean = (red[0] + red[1] + red[2] + red[3]) * (1.0f / DD);
    __syncthreads();
    float d0 = x0 - mean, d1 = x1 - mean;
    s = wave_sum(d0 * d0 + d1 * d1);
    if (lane == 0) red[wid] = s;
    __syncthreads();
    float var = (red[0] + red[1] + red[2] + red[3]) * (1.0f / DD);
    float inv = rsqrtf(var + 1e-5f);
    float n0 = d0 * inv * ln_g[tid] + ln_b[tid];
    float n1 = d1 * inv * ln_g[tid + 256] + ln_b[tid + 256];
    ldec[tid] = n0; ldec[tid + 256] = n1;
    if (slice == 0) {
        ws[WS_LDEC + b * DD + tid] = n0;
        ws[WS_LDEC + b * DD + tid + 256] = n1;
    }
    __syncthreads();

    int r = slice * 128 + (tid >> 1);   // 0..1023
    int m = r >> 9, rr = r & 511;
    int kh = tid & 1;
    const float* Wp = m ? ta_Wp : ua_Wp;
    const float* bp = m ? ta_bp : ua_bp;
    const float4* wr = (const float4*)(Wp + (size_t)rr * DD + kh * 256);
    const float4* hl = (const float4*)ldec + kh * 64;
    float acc = 0.f;
    #pragma unroll 8
    for (int i = 0; i < 64; i++) {
        float4 w = wr[i]; float4 h = hl[i];
        acc += w.x * h.x + w.y * h.y + w.z * h.z + w.w * h.w;
    }
    float tot = acc + __shfl_xor(acc, 1, 64);
    if (kh == 0) {
        float* dst = ws + (m ? WS_DEC_T : WS_DEC_U) + b * DD + rr;
        *dst = tot + bp[rr];
    }
}

// K2: utterance attention + u_cov + utter_index + p_gen
__global__ __launch_bounds__(256) void k2_uattn(
    const float* __restrict__ enc, const float* __restrict__ umask,
    const float* __restrict__ cov, const float* __restrict__ ua_v,
    const float* __restrict__ ua_wc, const float* __restrict__ pgen_W,
    const float* __restrict__ pgen_b,
    float* __restrict__ ws, float* __restrict__ out)
{
    int b = blockIdx.x, tid = threadIdx.x, wid = tid >> 6, lane = tid & 63;
    __shared__ __align__(16) float decu[DD], wcl[DD], vvl[DD], ldec[DD], uo[DD];
    __shared__ float sc[UU], attn[UU], red[4];
    decu[tid] = ws[WS_DEC_U + b * DD + tid]; decu[tid + 256] = ws[WS_DEC_U + b * DD + tid + 256];
    wcl[tid] = ua_wc[tid]; wcl[tid + 256] = ua_wc[tid + 256];
    vvl[tid] = ua_v[tid];  vvl[tid + 256] = ua_v[tid + 256];
    ldec[tid] = ws[WS_LDEC + b * DD + tid]; ldec[tid + 256] = ws[WS_LDEC + b * DD + tid + 256];
    __syncthreads();

    for (int u = wid; u < UU; u += 4) {
        float cb = cov[b * UU + u];
        const float* e = enc + ((size_t)b * UU + u) * DD;
        float p = 0.f;
        #pragma unroll
        for (int i = 0; i < DD / 64; i++) {
            int d = lane + i * 64;
            p += fast_tanh(e[d] + decu[d] + cb * wcl[d]) * vvl[d];
        }
        p = wave_sum(p);
        if (lane == 0) sc[u] = p;
    }
    __syncthreads();

    if (tid < 64) {
        float s = (tid < UU) ? sc[tid] : -INFINITY;
        float m = wave_max(s);
        float e = (tid < UU) ? __expf(s - m) : 0.f;
        float sum = wave_sum(e);
        float a_ = (e / sum) * ((tid < UU) ? umask[b * UU + tid] : 0.f);
        float nf = wave_sum(a_);
        float a = a_ / (nf == 0.f ? 1.f : nf);
        float av = (tid < UU) ? a : -INFINITY;
        float am = wave_max(av);
        unsigned long long ball = __ballot(av == am);
        int idx = __ffsll(ball) - 1;
        if (tid < UU) {
            attn[tid] = a;
            ws[WS_UATTN + b * UU + tid] = a;
            out[OUT_UCOV + b * UU + tid] = cov[b * UU + tid] + a;
        }
        if (tid == 0) {
            ((int*)ws)[WS_UIDX + b] = idx;
            out[OUT_UIDX + b] = (float)idx;
        }
    }
    __syncthreads();

    for (int d = tid; d < DD; d += 256) {
        float s = 0.f;
        #pragma unroll
        for (int u = 0; u < UU; u++) s += attn[u] * enc[((size_t)b * UU + u) * DD + d];
        uo[d] = s;
    }
    __syncthreads();

    float pp = uo[tid] * pgen_W[tid] + uo[tid + 256] * pgen_W[tid + 256]
             + ldec[tid] * pgen_W[DD + tid] + ldec[tid + 256] * pgen_W[DD + tid + 256];
    pp = wave_sum(pp);
    if (lane == 0) red[wid] = pp;
    __syncthreads();
    if (tid == 0) {
        float t = red[0] + red[1] + red[2] + red[3] + pgen_b[0];
        out[OUT_PGEN + b] = 1.f / (1.f + __expf(-t));
    }
}

// K3a: token attention raw scores. grid 2048: u = blk>>6, b = (blk&63)>>1, hf = blk&1.
__global__ __launch_bounds__(256, 4) void k3a_tscore(
    const float* __restrict__ tok, const float* __restrict__ tcov,
    const float* __restrict__ ta_v, const float* __restrict__ ta_wc,
    float* __restrict__ ws)
{
    int blk = blockIdx.x;
    int u = blk >> 6, r = blk & 63, b = r >> 1, hf = r & 1;
    int tid = threadIdx.x, wid = tid >> 6, lane = tid & 63;

    const float4* dec4 = (const float4*)(ws + WS_DEC_T + b * DD);
    const float4* wc4  = (const float4*)ta_wc;
    const float4* vv4  = (const float4*)ta_v;
    float4 dc0 = dec4[lane], dc1 = dec4[lane + 64];
    float4 wc0 = wc4[lane],  wc1 = wc4[lane + 64];
    float4 vv0 = vv4[lane],  vv1 = vv4[lane + 64];

    const float* base = tok + ((size_t)(u * BB + b)) * TK * DD;
    const float* tcb  = tcov + (size_t)(u * BB + b) * TK;
    int t0 = hf * 32 + wid * 8;

    float4 x[8][2];
    float tc[8];
    #pragma unroll
    for (int j = 0; j < 8; j++) {
        const float4* row = (const float4*)(base + (size_t)(t0 + j) * DD);
        x[j][0] = row[lane];
        x[j][1] = row[lane + 64];
        tc[j] = tcb[t0 + j];
    }
    #pragma unroll
    for (int j = 0; j < 8; j++) {
        float p = 0.f;
        float4 a = x[j][0], c = x[j][1];
        float t_ = tc[j];
        p += fast_tanh(a.x + dc0.x + t_ * wc0.x) * vv0.x;
        p += fast_tanh(a.y + dc0.y + t_ * wc0.y) * vv0.y;
        p += fast_tanh(a.z + dc0.z + t_ * wc0.z) * vv0.z;
        p += fast_tanh(a.w + dc0.w + t_ * wc0.w) * vv0.w;
        p += fast_tanh(c.x + dc1.x + t_ * wc1.x) * vv1.x;
        p += fast_tanh(c.y + dc1.y + t_ * wc1.y) * vv1.y;
        p += fast_tanh(c.z + dc1.z + t_ * wc1.z) * vv1.z;
        p += fast_tanh(c.w + dc1.w + t_ * wc1.w) * vv1.w;
        p = wave_sum(p);
        if (lane == 0) ws[WS_TSC + (size_t)(u * BB + b) * TK + t0 + j] = p;
    }
}

// K3b: per-(u,b) softmax over 64 scores + next_tok_cov.
__global__ __launch_bounds__(256) void k3b_tsoftmax(
    const float* __restrict__ tmask, const float* __restrict__ tcov,
    float* __restrict__ ws, float* __restrict__ out)
{
    int tid = threadIdx.x, wid = tid >> 6, lane = tid & 63;
    int g = blockIdx.x * 4 + wid;  // 0..1023 = u*32+b
    float s = ws[WS_TSC + (size_t)g * TK + lane];
    float m = wave_max(s);
    float e = __expf(s - m);
    float sum = wave_sum(e);
    float a_ = (e / sum) * tmask[(size_t)g * TK + lane];
    float nf = wave_sum(a_);
    float a = a_ / (nf == 0.f ? 1.f : nf);
    ws[WS_TATTN + (size_t)g * TK + lane] = a;
    out[OUT_NTC + (size_t)g * TK + lane] = tcov[(size_t)g * TK + lane] + a;
}

// K4a: gather selected utterance attn, write TAD, compute target_out -> ws
__global__ __launch_bounds__(256) void k4a_gather(
    const float* __restrict__ tok, float* __restrict__ ws, float* __restrict__ out)
{
    int b = blockIdx.x, tid = threadIdx.x;
    __shared__ float at[TK];
    int u = ((const int*)ws)[WS_UIDX + b];
    if (tid < TK) {
        float a = ws[WS_TATTN + (size_t)(u * BB + b) * TK + tid];
        at[tid] = a;
        out[OUT_TAD + b * TK + tid] = a;
    }
    __syncthreads();
    const float* base = tok + ((size_t)(u * BB + b)) * TK * DD;
    float a0 = 0.f, a1 = 0.f;
    #pragma unroll 8
    for (int t = 0; t < TK; t++) {
        float a = at[t];
        a0 += a * base[(size_t)t * DD + tid];
        a1 += a * base[(size_t)t * DD + tid + 256];
    }
    ws[WS_TOUT + b * DD + tid] = a0;
    ws[WS_TOUT + b * DD + tid + 256] = a1;
}

// K4b: h = [target_out, ldec] @ out1_W^T + b.
__global__ __launch_bounds__(256) void k4b_h(
    const float* __restrict__ out1_W, const float* __restrict__ out1_b,
    float* __restrict__ ws)
{
    int slice = blockIdx.x >> 5, b = blockIdx.x & 31;
    int tid = threadIdx.x;
    __shared__ __align__(16) float hcat[2 * DD];
    hcat[tid]       = ws[WS_TOUT + b * DD + tid];
    hcat[tid + 256] = ws[WS_TOUT + b * DD + tid + 256];
    hcat[tid + 512] = ws[WS_LDEC + b * DD + tid];
    hcat[tid + 768] = ws[WS_LDEC + b * DD + tid + 256];
    __syncthreads();

    int row = slice * 128 + (tid >> 1);
    int kh = tid & 1;
    const float4* wr = (const float4*)(out1_W + (size_t)row * (2 * DD) + kh * 512);
    const float4* hl = (const float4*)hcat + kh * 128;
    float acc = 0.f;
    #pragma unroll 8
    for (int i = 0; i < 128; i++) {
        float4 w = wr[i]; float4 h = hl[i];
        acc += w.x * h.x + w.y * h.y + w.z * h.z + w.w * h.w;
    }
    float tot = acc + __shfl_xor(acc, 1, 64);
    if (kh == 0) ws[WS_H + b * DD + row] = tot + out1_b[row];
}

// K5: real GEMM. C[32,VV] = h[32,512] @ W2^T, exp fused, per-block psums.
// Block: Ntile=256 v, all 32 b. 256 threads, thread tile 4b x 8v.
// LDS: W2t[k][v] stride 260, ht[k][b] stride 36 (both 16B-aligned rows).
__global__ __launch_bounds__(256) void k5_gemm(
    const float* __restrict__ W2, const float* __restrict__ b2,
    float* __restrict__ ws, float* __restrict__ out)
{
    __shared__ __align__(16) float W2t[32 * 260];
    __shared__ __align__(16) float htl[32 * 36];
    __shared__ float pr[32 * 33];

    int tid = threadIdx.x;
    int bg = tid >> 5;          // 0..7 -> b0 = bg*4
    int vg = tid & 31;          // v0 = vg*8
    int b0 = bg * 4;
    int vg8 = vg * 8;
    int v0base = blockIdx.x * N5TILE;

    int kq = (tid & 7) * 4;     // k-offset within chunk for staging
    int sr = tid >> 3;          // 0..31: v-row (per pass) / b-row for h staging

    float acc[4][8];
    #pragma unroll
    for (int i = 0; i < 4; i++)
        #pragma unroll
        for (int j = 0; j < 8; j++) acc[i][j] = 0.f;

    for (int kt = 0; kt < 16; kt++) {
        int k0 = kt * 32;
        // h staging: thread (sr=b, kq): transposed write
        {
            float4 hv = *(const float4*)(ws + WS_H + sr * DD + k0 + kq);
            htl[(kq + 0) * 36 + sr] = hv.x;
            htl[(kq + 1) * 36 + sr] = hv.y;
            htl[(kq + 2) * 36 + sr] = hv.z;
            htl[(kq + 3) * 36 + sr] = hv.w;
        }
        // W2 staging: 8 passes x 32 v-rows, transposed write
        #pragma unroll
        for (int p = 0; p < 8; p++) {
            int lv = p * 32 + sr;
            int v = v0base + lv;
            float4 wv = {0.f, 0.f, 0.f, 0.f};
            if (v < VV) wv = *(const float4*)(W2 + (size_t)v * DD + k0 + kq);
            W2t[(kq + 0) * 260 + lv] = wv.x;
            W2t[(kq + 1) * 260 + lv] = wv.y;
            W2t[(kq + 2) * 260 + lv] = wv.z;
            W2t[(kq + 3) * 260 + lv] = wv.w;
        }
        __syncthreads();
        #pragma unroll 4
        for (int k = 0; k < 32; k++) {
            float4 hb = *(const float4*)&htl[k * 36 + b0];
            float4 wa = *(const float4*)&W2t[k * 260 + vg8];
            float4 wb = *(const float4*)&W2t[k * 260 + vg8 + 4];
            acc[0][0] += hb.x * wa.x; acc[0][1] += hb.x * wa.y; acc[0][2] += hb.x * wa.z; acc[0][3] += hb.x * wa.w;
            acc[0][4] += hb.x * wb.x; acc[0][5] += hb.x * wb.y; acc[0][6] += hb.x * wb.z; acc[0][7] += hb.x * wb.w;
            acc[1][0] += hb.y * wa.x; acc[1][1] += hb.y * wa.y; acc[1][2] += hb.y * wa.z; acc[1][3] += hb.y * wa.w;
            acc[1][4] += hb.y * wb.x; acc[1][5] += hb.y * wb.y; acc[1][6] += hb.y * wb.z; acc[1][7] += hb.y * wb.w;
            acc[2][0] += hb.z * wa.x; acc[2][1] += hb.z * wa.y; acc[2][2] += hb.z * wa.z; acc[2][3] += hb.z * wa.w;
            acc[2][4] += hb.z * wb.x; acc[2][5] += hb.z * wb.y; acc[2][6] += hb.z * wb.z; acc[2][7] += hb.z * wb.w;
            acc[3][0] += hb.w * wa.x; acc[3][1] += hb.w * wa.y; acc[3][2] += hb.w * wa.z; acc[3][3] += hb.w * wa.w;
            acc[3][4] += hb.w * wb.x; acc[3][5] += hb.w * wb.y; acc[3][6] += hb.w * wb.z; acc[3][7] += hb.w * wb.w;
        }
        __syncthreads();
    }

    // epilogue: exp + store + per-b partial sums
    int v0 = v0base + vg8;
    float b2v[8];
    #pragma unroll
    for (int vi = 0; vi < 8; vi++) b2v[vi] = (v0 + vi < VV) ? b2[v0 + vi] : 0.f;

    float esum[4];
    #pragma unroll
    for (int bi = 0; bi < 4; bi++) {
        float es = 0.f;
        float* op = out + (size_t)(b0 + bi) * VV + v0;
        #pragma unroll
        for (int vi = 0; vi < 8; vi++) {
            if (v0 + vi < VV) {
                float e = __expf(acc[bi][vi] + b2v[vi]);
                op[vi] = e;
                es += e;
            }
        }
        esum[bi] = es;
    }
    #pragma unroll
    for (int bi = 0; bi < 4; bi++) pr[(b0 + bi) * 33 + vg] = esum[bi];
    __syncthreads();
    if (tid < 32) {
        float s = 0.f;
        #pragma unroll 8
        for (int j = 0; j < 32; j++) s += pr[tid * 33 + j];
        ws[WS_PSUM + blockIdx.x * 32 + tid] = s;
    }
}

// K_sum: reduce psum[K5_GRID][32] -> ws_sums[32] (stores reciprocal)
__global__ __launch_bounds__(256) void k_sum(float* __restrict__ ws)
{
    int tid = threadIdx.x;
    int b = tid & 31, c = tid >> 5;  // 8 chunks of 25 blocks
    __shared__ float red8[8][32];
    float p = 0.f;
    int g0 = c * 25, g1 = (c + 1) * 25;
    if (g1 > K5_GRID) g1 = K5_GRID;
    for (int g = g0; g < g1; g++) p += ws[WS_PSUM + g * 32 + b];
    red8[c][b] = p;
    __syncthreads();
    if (tid < 32) {
        float s = 0.f;
        #pragma unroll
        for (int c2 = 0; c2 < 8; c2++) s += red8[c2][tid];
        ws[WS_SUMS + tid] = 1.0f / s;
    }
}

// K_scale: vocab_dist = exp(logit) * (1/sum_b)
__global__ __launch_bounds__(256) void k_scale(const float* __restrict__ ws, float* __restrict__ out)
{
    int b = blockIdx.y;
    int v = blockIdx.x * 256 + threadIdx.x;
    if (v < VV) out[(size_t)b * VV + v] *= ws[WS_SUMS + b];
}

extern "C" void kernel_launch(void* const* d_in, const int* in_sizes, int n_in,
                              void* d_out, int out_size, void* d_ws, size_t ws_size,
                              hipStream_t stream) {
    const float* tf      = (const float*)d_in[0];
    const float* enc     = (const float*)d_in[2];
    const float* umask   = (const float*)d_in[3];
    const float* tok     = (const float*)d_in[4];
    const float* tmask   = (const float*)d_in[5];
    const float* cov     = (const float*)d_in[6];
    const float* tcov    = (const float*)d_in[7];
    const float* ua_Wp   = (const float*)d_in[8];
    const float* ua_bp   = (const float*)d_in[9];
    const float* ua_v    = (const float*)d_in[10];
    const float* ua_wc   = (const float*)d_in[11];
    const float* ta_Wp   = (const float*)d_in[12];
    const float* ta_bp   = (const float*)d_in[13];
    const float* ta_v    = (const float*)d_in[14];
    const float* ta_wc   = (const float*)d_in[15];
    const float* pgen_W  = (const float*)d_in[16];
    const float* pgen_b  = (const float*)d_in[17];
    const float* out1_W  = (const float*)d_in[18];
    const float* out1_b  = (const float*)d_in[19];
    const float* out2_W  = (const float*)d_in[20];
    const float* out2_b  = (const float*)d_in[21];
    const float* ln_g    = (const float*)d_in[22];
    const float* ln_b    = (const float*)d_in[23];

    float* ws  = (float*)d_ws;
    float* out = (float*)d_out;

    k1_ln_proj<<<dim3(256), dim3(256), 0, stream>>>(tf, ln_g, ln_b, ua_Wp, ua_bp, ta_Wp, ta_bp, ws);
    k2_uattn<<<dim3(BB), dim3(256), 0, stream>>>(enc, umask, cov, ua_v, ua_wc, pgen_W, pgen_b, ws, out);
    k3a_tscore<<<dim3(2048), dim3(256), 0, stream>>>(tok, tcov, ta_v, ta_wc, ws);
    k3b_tsoftmax<<<dim3(256), dim3(256), 0, stream>>>(tmask, tcov, ws, out);
    k4a_gather<<<dim3(BB), dim3(256), 0, stream>>>(tok, ws, out);
    k4b_h<<<dim3(128), dim3(256), 0, stream>>>(out1_W, out1_b, ws);
    k5_gemm<<<dim3(K5_GRID), dim3(256), 0, stream>>>(out2_W, out2_b, ws, out);
    k_sum<<<dim3(1), dim3(256), 0, stream>>>(ws);
    k_scale<<<dim3(197, 32), dim3(256), 0, stream>>>(ws, out);
}

// Round 4
// 413.941 us; speedup vs baseline: 1.5576x; 1.1069x over previous
//
#include <hip/hip_runtime.h>
#include <math.h>

#define BB 32
#define TDEC 64
#define UU 32
#define TK 64
#define DD 512
#define VV 50257
#define K5_TPB 128
#define K5_GRID 393          // ceil(50257/128)
#define NPSUM (K5_GRID * 2)  // per-wave psums

// ---- workspace layout (float indices) ----
#define WS_LDEC   0          // B*D
#define WS_DEC_U  16384      // B*D
#define WS_DEC_T  32768      // B*D
#define WS_UATTN  49152      // B*U
#define WS_UIDX   50176      // B (int)
#define WS_TATTN  50208      // U*B*TK
#define WS_TOUT   115744     // B*D
#define WS_H      132128     // B*D
#define WS_PSUM   148512     // NPSUM*32 = 25152
#define WS_SUMS   173664     // 32 (stores 1/sum)

// ---- output layout (float indices) ----
#define OUT_VOCAB 0
#define OUT_TAD   1608224
#define OUT_PGEN  1610272
#define OUT_UCOV  1610304
#define OUT_NTC   1611328
#define OUT_UIDX  1676864

__device__ __forceinline__ float wave_sum(float v) {
    #pragma unroll
    for (int off = 32; off > 0; off >>= 1) v += __shfl_xor(v, off, 64);
    return v;
}
__device__ __forceinline__ float wave_max(float v) {
    #pragma unroll
    for (int off = 32; off > 0; off >>= 1) v = fmaxf(v, __shfl_xor(v, off, 64));
    return v;
}
__device__ __forceinline__ float fast_tanh(float x) {
    float e2 = __expf(2.0f * x);
    return 1.0f - 2.0f * __builtin_amdgcn_rcpf(e2 + 1.0f);
}

// K1: LN of last timestep (recomputed per block) + slice of both Wp projections.
__global__ __launch_bounds__(256) void k1_ln_proj(
    const float* __restrict__ tf, const float* __restrict__ ln_g, const float* __restrict__ ln_b,
    const float* __restrict__ ua_Wp, const float* __restrict__ ua_bp,
    const float* __restrict__ ta_Wp, const float* __restrict__ ta_bp,
    float* __restrict__ ws)
{
    int b = blockIdx.x >> 3, slice = blockIdx.x & 7;
    int tid = threadIdx.x, wid = tid >> 6, lane = tid & 63;
    __shared__ __align__(16) float ldec[DD];
    __shared__ float red[4];
    const float* x = tf + ((size_t)b * TDEC + (TDEC - 1)) * DD;
    float x0 = x[tid], x1 = x[tid + 256];

    float s = wave_sum(x0 + x1);
    if (lane == 0) red[wid] = s;
    __syncthreads();
    float mean = (red[0] + red[1] + red[2] + red[3]) * (1.0f / DD);
    __syncthreads();
    float d0 = x0 - mean, d1 = x1 - mean;
    s = wave_sum(d0 * d0 + d1 * d1);
    if (lane == 0) red[wid] = s;
    __syncthreads();
    float var = (red[0] + red[1] + red[2] + red[3]) * (1.0f / DD);
    float inv = rsqrtf(var + 1e-5f);
    float n0 = d0 * inv * ln_g[tid] + ln_b[tid];
    float n1 = d1 * inv * ln_g[tid + 256] + ln_b[tid + 256];
    ldec[tid] = n0; ldec[tid + 256] = n1;
    if (slice == 0) {
        ws[WS_LDEC + b * DD + tid] = n0;
        ws[WS_LDEC + b * DD + tid + 256] = n1;
    }
    __syncthreads();

    int r = slice * 128 + (tid >> 1);   // 0..1023
    int m = r >> 9, rr = r & 511;
    int kh = tid & 1;
    const float* Wp = m ? ta_Wp : ua_Wp;
    const float* bp = m ? ta_bp : ua_bp;
    const float4* wr = (const float4*)(Wp + (size_t)rr * DD + kh * 256);
    const float4* hl = (const float4*)ldec + kh * 64;
    float acc = 0.f;
    #pragma unroll 8
    for (int i = 0; i < 64; i++) {
        float4 w = wr[i]; float4 h = hl[i];
        acc += w.x * h.x + w.y * h.y + w.z * h.z + w.w * h.w;
    }
    float tot = acc + __shfl_xor(acc, 1, 64);
    if (kh == 0) {
        float* dst = ws + (m ? WS_DEC_T : WS_DEC_U) + b * DD + rr;
        *dst = tot + bp[rr];
    }
}

// K2: utterance attention + u_cov + utter_index + p_gen (float4 everywhere)
__global__ __launch_bounds__(256) void k2_uattn(
    const float* __restrict__ enc, const float* __restrict__ umask,
    const float* __restrict__ cov, const float* __restrict__ ua_v,
    const float* __restrict__ ua_wc, const float* __restrict__ pgen_W,
    const float* __restrict__ pgen_b,
    float* __restrict__ ws, float* __restrict__ out)
{
    int b = blockIdx.x, tid = threadIdx.x, wid = tid >> 6, lane = tid & 63;
    __shared__ __align__(16) float4 decu4[128], wcl4[128], vvl4[128], ldec4[128];
    __shared__ __align__(16) float4 part[2][128], uo4[128];
    __shared__ float sc[UU], attn[UU], red[4];

    if (tid < 128) {
        decu4[tid] = ((const float4*)(ws + WS_DEC_U + b * DD))[tid];
        wcl4[tid]  = ((const float4*)ua_wc)[tid];
        vvl4[tid]  = ((const float4*)ua_v)[tid];
        ldec4[tid] = ((const float4*)(ws + WS_LDEC + b * DD))[tid];
    }
    __syncthreads();

    for (int u = wid; u < UU; u += 4) {
        float cb = cov[b * UU + u];
        const float4* e4 = (const float4*)(enc + ((size_t)b * UU + u) * DD);
        float p = 0.f;
        #pragma unroll
        for (int i = 0; i < 2; i++) {
            int idx = lane + i * 64;
            float4 x = e4[idx], dc = decu4[idx], wc = wcl4[idx], vv = vvl4[idx];
            p += fast_tanh(x.x + dc.x + cb * wc.x) * vv.x;
            p += fast_tanh(x.y + dc.y + cb * wc.y) * vv.y;
            p += fast_tanh(x.z + dc.z + cb * wc.z) * vv.z;
            p += fast_tanh(x.w + dc.w + cb * wc.w) * vv.w;
        }
        p = wave_sum(p);
        if (lane == 0) sc[u] = p;
    }
    __syncthreads();

    if (tid < 64) {
        float s = (tid < UU) ? sc[tid] : -INFINITY;
        float m = wave_max(s);
        float e = (tid < UU) ? __expf(s - m) : 0.f;
        float sum = wave_sum(e);
        float a_ = (e / sum) * ((tid < UU) ? umask[b * UU + tid] : 0.f);
        float nf = wave_sum(a_);
        float a = a_ / (nf == 0.f ? 1.f : nf);
        float av = (tid < UU) ? a : -INFINITY;
        float am = wave_max(av);
        unsigned long long ball = __ballot(av == am);
        int idx = __ffsll(ball) - 1;
        if (tid < UU) {
            attn[tid] = a;
            ws[WS_UATTN + b * UU + tid] = a;
            out[OUT_UCOV + b * UU + tid] = cov[b * UU + tid] + a;
        }
        if (tid == 0) {
            ((int*)ws)[WS_UIDX + b] = idx;
            out[OUT_UIDX + b] = (float)idx;
        }
    }
    __syncthreads();

    // uo = attn @ enc[b]  (2-way u-split, float4 columns)
    {
        int cid = tid & 127, half = tid >> 7;
        const float4* e4 = (const float4*)(enc + (size_t)b * UU * DD);
        float4 s = {0.f, 0.f, 0.f, 0.f};
        #pragma unroll
        for (int uu = 0; uu < 16; uu++) {
            int u = half * 16 + uu;
            float a = attn[u];
            float4 x = e4[(size_t)u * 128 + cid];
            s.x += a * x.x; s.y += a * x.y; s.z += a * x.z; s.w += a * x.w;
        }
        part[half][cid] = s;
    }
    __syncthreads();
    if (tid < 128) {
        float4 p0 = part[0][tid], p1 = part[1][tid];
        float4 r = {p0.x + p1.x, p0.y + p1.y, p0.z + p1.z, p0.w + p1.w};
        uo4[tid] = r;
    }
    __syncthreads();

    float pp;
    if (tid < 128) {
        float4 v = uo4[tid];
        float4 pw = ((const float4*)pgen_W)[tid];
        pp = v.x * pw.x + v.y * pw.y + v.z * pw.z + v.w * pw.w;
    } else {
        int t2 = tid - 128;
        float4 v = ldec4[t2];
        float4 pw = ((const float4*)pgen_W)[128 + t2];
        pp = v.x * pw.x + v.y * pw.y + v.z * pw.z + v.w * pw.w;
    }
    pp = wave_sum(pp);
    if (lane == 0) red[wid] = pp;
    __syncthreads();
    if (tid == 0) {
        float t = red[0] + red[1] + red[2] + red[3] + pgen_b[0];
        out[OUT_PGEN + b] = 1.f / (1.f + __expf(-t));
    }
}

// K3: fused token attention per (u,b): scores + softmax + TATTN + NTC. grid 1024.
__global__ __launch_bounds__(256) void k3_fused(
    const float* __restrict__ tok, const float* __restrict__ tmask,
    const float* __restrict__ tcov, const float* __restrict__ ta_v,
    const float* __restrict__ ta_wc,
    float* __restrict__ ws, float* __restrict__ out)
{
    int g = blockIdx.x;            // u*32 + b
    int b = g & 31;
    int tid = threadIdx.x, wid = tid >> 6, lane = tid & 63;
    __shared__ float sc[TK];

    const float4* dec4 = (const float4*)(ws + WS_DEC_T + b * DD);
    const float4* wc4  = (const float4*)ta_wc;
    const float4* vv4  = (const float4*)ta_v;
    float4 dc0 = dec4[lane], dc1 = dec4[lane + 64];
    float4 wc0 = wc4[lane],  wc1 = wc4[lane + 64];
    float4 vv0 = vv4[lane],  vv1 = vv4[lane + 64];

    const float* base = tok + (size_t)g * TK * DD;
    const float* tcb  = tcov + (size_t)g * TK;

    #pragma unroll
    for (int grp = 0; grp < 4; grp++) {
        int t0 = wid * 16 + grp * 4;
        float4 x0[4], x1[4];
        float tc[4];
        #pragma unroll
        for (int j = 0; j < 4; j++) {
            const float4* row = (const float4*)(base + (size_t)(t0 + j) * DD);
            x0[j] = row[lane];
            x1[j] = row[lane + 64];
            tc[j] = tcb[t0 + j];
        }
        #pragma unroll
        for (int j = 0; j < 4; j++) {
            float t_ = tc[j];
            float4 a = x0[j], c = x1[j];
            float p = 0.f;
            p += fast_tanh(a.x + dc0.x + t_ * wc0.x) * vv0.x;
            p += fast_tanh(a.y + dc0.y + t_ * wc0.y) * vv0.y;
            p += fast_tanh(a.z + dc0.z + t_ * wc0.z) * vv0.z;
            p += fast_tanh(a.w + dc0.w + t_ * wc0.w) * vv0.w;
            p += fast_tanh(c.x + dc1.x + t_ * wc1.x) * vv1.x;
            p += fast_tanh(c.y + dc1.y + t_ * wc1.y) * vv1.y;
            p += fast_tanh(c.z + dc1.z + t_ * wc1.z) * vv1.z;
            p += fast_tanh(c.w + dc1.w + t_ * wc1.w) * vv1.w;
            p = wave_sum(p);
            if (lane == 0) sc[t0 + j] = p;
        }
    }
    __syncthreads();

    if (tid < 64) {
        float s = sc[tid];
        float m = wave_max(s);
        float e = __expf(s - m);
        float sum = wave_sum(e);
        float a_ = (e / sum) * tmask[(size_t)g * TK + tid];
        float nf = wave_sum(a_);
        float a = a_ / (nf == 0.f ? 1.f : nf);
        ws[WS_TATTN + (size_t)g * TK + tid] = a;
        out[OUT_NTC + (size_t)g * TK + tid] = tcb[tid] + a;
    }
}

// K4a: gather selected utterance attn, write TAD, target_out (float4, 2-way t-split)
__global__ __launch_bounds__(256) void k4a_gather(
    const float* __restrict__ tok, float* __restrict__ ws, float* __restrict__ out)
{
    int b = blockIdx.x, tid = threadIdx.x;
    __shared__ float at[TK];
    __shared__ __align__(16) float4 part[2][128];
    int u = ((const int*)ws)[WS_UIDX + b];
    if (tid < TK) {
        float a = ws[WS_TATTN + (size_t)(u * BB + b) * TK + tid];
        at[tid] = a;
        out[OUT_TAD + b * TK + tid] = a;
    }
    __syncthreads();
    const float4* base4 = (const float4*)(tok + ((size_t)(u * BB + b)) * TK * DD);
    int cid = tid & 127, th = tid >> 7;
    float4 s = {0.f, 0.f, 0.f, 0.f};
    #pragma unroll 8
    for (int tt = 0; tt < 32; tt++) {
        int t = th * 32 + tt;
        float a = at[t];
        float4 x = base4[(size_t)t * 128 + cid];
        s.x += a * x.x; s.y += a * x.y; s.z += a * x.z; s.w += a * x.w;
    }
    part[th][cid] = s;
    __syncthreads();
    if (tid < 128) {
        float4 p0 = part[0][tid], p1 = part[1][tid];
        float4 r = {p0.x + p1.x, p0.y + p1.y, p0.z + p1.z, p0.w + p1.w};
        ((float4*)(ws + WS_TOUT + b * DD))[tid] = r;
    }
}

// K4b: h = [target_out, ldec] @ out1_W^T + b.
__global__ __launch_bounds__(256) void k4b_h(
    const float* __restrict__ out1_W, const float* __restrict__ out1_b,
    float* __restrict__ ws)
{
    int slice = blockIdx.x >> 5, b = blockIdx.x & 31;
    int tid = threadIdx.x;
    __shared__ __align__(16) float hcat[2 * DD];
    hcat[tid]       = ws[WS_TOUT + b * DD + tid];
    hcat[tid + 256] = ws[WS_TOUT + b * DD + tid + 256];
    hcat[tid + 512] = ws[WS_LDEC + b * DD + tid];
    hcat[tid + 768] = ws[WS_LDEC + b * DD + tid + 256];
    __syncthreads();

    int row = slice * 128 + (tid >> 1);
    int kh = tid & 1;
    const float4* wr = (const float4*)(out1_W + (size_t)row * (2 * DD) + kh * 512);
    const float4* hl = (const float4*)hcat + kh * 128;
    float acc = 0.f;
    #pragma unroll 8
    for (int i = 0; i < 128; i++) {
        float4 w = wr[i]; float4 h = hl[i];
        acc += w.x * h.x + w.y * h.y + w.z * h.z + w.w * h.w;
    }
    float tot = acc + __shfl_xor(acc, 1, 64);
    if (kh == 0) ws[WS_H + b * DD + row] = tot + out1_b[row];
}

// K5: streaming GEMV. One v-row per thread; h^T (64KB) fully in LDS, broadcast reads.
// exp fused; per-wave psums.
__global__ __launch_bounds__(128) void k5_gemv(
    const float* __restrict__ W2, const float* __restrict__ b2,
    float* __restrict__ ws, float* __restrict__ out)
{
    __shared__ __align__(16) float hT[DD * 32];   // 64 KB: hT[k*32 + b]
    int tid = threadIdx.x, wid = tid >> 6;

    // stage h transposed: thread t -> b = t>>2, k-quarter = (t&3)*128
    {
        int bb = tid >> 2;
        int kq = (tid & 3) * 128;
        const float4* hp = (const float4*)(ws + WS_H + bb * DD + kq);
        #pragma unroll
        for (int i = 0; i < 32; i++) {
            float4 hv = hp[i];
            int k = kq + i * 4;
            hT[(k + 0) * 32 + bb] = hv.x;
            hT[(k + 1) * 32 + bb] = hv.y;
            hT[(k + 2) * 32 + bb] = hv.z;
            hT[(k + 3) * 32 + bb] = hv.w;
        }
    }
    __syncthreads();

    int v = blockIdx.x * K5_TPB + tid;
    bool valid = v < VV;
    int vld = valid ? v : (VV - 1);
    const float4* wrow = (const float4*)(W2 + (size_t)vld * DD);

    float acc[32];
    #pragma unroll
    for (int i = 0; i < 32; i++) acc[i] = 0.f;

    #pragma unroll 4
    for (int kt = 0; kt < 128; kt++) {
        float4 w = wrow[kt];
        #pragma unroll
        for (int kk = 0; kk < 4; kk++) {
            float wk = (kk == 0) ? w.x : (kk == 1) ? w.y : (kk == 2) ? w.z : w.w;
            const float4* hrow = (const float4*)&hT[(kt * 4 + kk) * 32];
            #pragma unroll
            for (int b0 = 0; b0 < 8; b0++) {
                float4 hb = hrow[b0];
                acc[b0 * 4 + 0] += wk * hb.x;
                acc[b0 * 4 + 1] += wk * hb.y;
                acc[b0 * 4 + 2] += wk * hb.z;
                acc[b0 * 4 + 3] += wk * hb.w;
            }
        }
    }

    float bias = valid ? b2[v] : 0.f;
    #pragma unroll
    for (int b = 0; b < 32; b++) {
        float e = valid ? __expf(acc[b] + bias) : 0.f;
        acc[b] = e;
        if (valid) out[(size_t)b * VV + v] = e;
    }
    #pragma unroll
    for (int b = 0; b < 32; b++) acc[b] = wave_sum(acc[b]);
    if ((tid & 63) == 0) {
        float* ps = ws + WS_PSUM + ((size_t)blockIdx.x * 2 + wid) * 32;
        #pragma unroll
        for (int b = 0; b < 32; b++) ps[b] = acc[b];
    }
}

// K_sum: reduce psum[NPSUM][32] -> ws_sums[32] (stores reciprocal)
__global__ __launch_bounds__(256) void k_sum(float* __restrict__ ws)
{
    int tid = threadIdx.x;
    int b = tid & 31, c = tid >> 5;  // 8 chunks of 99
    __shared__ float red8[8][32];
    float p = 0.f;
    int g0 = c * 99, g1 = (c + 1) * 99;
    if (g1 > NPSUM) g1 = NPSUM;
    for (int g = g0; g < g1; g++) p += ws[WS_PSUM + g * 32 + b];
    red8[c][b] = p;
    __syncthreads();
    if (tid < 32) {
        float s = 0.f;
        #pragma unroll
        for (int c2 = 0; c2 < 8; c2++) s += red8[c2][tid];
        ws[WS_SUMS + tid] = 1.0f / s;
    }
}

// K_scale: vocab_dist = exp(logit) * (1/sum_b)
__global__ __launch_bounds__(256) void k_scale(const float* __restrict__ ws, float* __restrict__ out)
{
    int b = blockIdx.y;
    int v = blockIdx.x * 256 + threadIdx.x;
    if (v < VV) out[(size_t)b * VV + v] *= ws[WS_SUMS + b];
}

extern "C" void kernel_launch(void* const* d_in, const int* in_sizes, int n_in,
                              void* d_out, int out_size, void* d_ws, size_t ws_size,
                              hipStream_t stream) {
    const float* tf      = (const float*)d_in[0];
    const float* enc     = (const float*)d_in[2];
    const float* umask   = (const float*)d_in[3];
    const float* tok     = (const float*)d_in[4];
    const float* tmask   = (const float*)d_in[5];
    const float* cov     = (const float*)d_in[6];
    const float* tcov    = (const float*)d_in[7];
    const float* ua_Wp   = (const float*)d_in[8];
    const float* ua_bp   = (const float*)d_in[9];
    const float* ua_v    = (const float*)d_in[10];
    const float* ua_wc   = (const float*)d_in[11];
    const float* ta_Wp   = (const float*)d_in[12];
    const float* ta_bp   = (const float*)d_in[13];
    const float* ta_v    = (const float*)d_in[14];
    const float* ta_wc   = (const float*)d_in[15];
    const float* pgen_W  = (const float*)d_in[16];
    const float* pgen_b  = (const float*)d_in[17];
    const float* out1_W  = (const float*)d_in[18];
    const float* out1_b  = (const float*)d_in[19];
    const float* out2_W  = (const float*)d_in[20];
    const float* out2_b  = (const float*)d_in[21];
    const float* ln_g    = (const float*)d_in[22];
    const float* ln_b    = (const float*)d_in[23];

    float* ws  = (float*)d_ws;
    float* out = (float*)d_out;

    k1_ln_proj<<<dim3(256), dim3(256), 0, stream>>>(tf, ln_g, ln_b, ua_Wp, ua_bp, ta_Wp, ta_bp, ws);
    k2_uattn<<<dim3(BB), dim3(256), 0, stream>>>(enc, umask, cov, ua_v, ua_wc, pgen_W, pgen_b, ws, out);
    k3_fused<<<dim3(UU * BB), dim3(256), 0, stream>>>(tok, tmask, tcov, ta_v, ta_wc, ws, out);
    k4a_gather<<<dim3(BB), dim3(256), 0, stream>>>(tok, ws, out);
    k4b_h<<<dim3(128), dim3(256), 0, stream>>>(out1_W, out1_b, ws);
    k5_gemv<<<dim3(K5_GRID), dim3(K5_TPB), 0, stream>>>(out2_W, out2_b, ws, out);
    k_sum<<<dim3(1), dim3(256), 0, stream>>>(ws);
    k_scale<<<dim3(197, 32), dim3(256), 0, stream>>>(ws, out);
}